// Round 5
// baseline (78.439 us; speedup 1.0000x reference)
//
#include <hip/hip_runtime.h>

// ---------------------------------------------------------------------------
// LMU fused cell on MI355X (gfx950).  Round 5: single GEMM, no A-pack pass.
//   new_h = sigmoid([x|h|m] @ [Wx|Wh|Wm@AT]^T + u*(Wm@BT)^T)
//   new_m = m @ AT^T + u*BT^T     u = [x|h|m].e  (via MFMA vs epack col 0)
// lmu_gemm: BM=128 BN=128 BK=64x14. A reg-staged f32->bf16 (issue-early/
//   commit-late), B via global_load_lds, LDS 64KB dbuf -> 2 blocks/CU.
//   u by 2 extra MFMAs/chunk on wc==0 waves; new_m side-GEMM chunks 10-13
//   with B-frags direct from L2.
// ---------------------------------------------------------------------------

typedef __bf16 bf16;
typedef bf16  bf16x8 __attribute__((ext_vector_type(8)));
typedef float f32x4  __attribute__((ext_vector_type(4)));
typedef unsigned short u16;

#define BATCH 16384
// ws offsets (u16 units)
#define WPACK 0          // [896/8][512][8] = 458752  (k>=640 = Wm@AT)
#define ATPACK 458752    // [256/8][256][8] = 65536
#define WUOFF 524288     // 512 f32 (1024 u16)
#define EPACK 525312     // [112][16][8] = 14336 (col0 = e, rest 0)
#define PACK_ITEMS 408064   // 327680 + 65536 + 512 + 14336 = 1594*256

__device__ __forceinline__ u16 f2bf(float f) {
  unsigned u = __builtin_bit_cast(unsigned, f);
  u += 0x7FFFu + ((u >> 16) & 1u);   // RNE
  return (u16)(u >> 16);
}

__device__ __forceinline__ void gload16(const u16* g, u16* l) {
  __builtin_amdgcn_global_load_lds(
      (const __attribute__((address_space(1))) unsigned int*)g,
      (__attribute__((address_space(3))) unsigned int*)l, 16, 0, 0);
}

// ---------------- prologue 1: pack Wx|Wh, AT, wu=Wm@BT, epack --------------
__global__ __launch_bounds__(256) void lmu_pack(
    const float* __restrict__ Wx, const float* __restrict__ Wh,
    const float* __restrict__ Wm, const float* __restrict__ AT,
    const float* __restrict__ BT, const float* __restrict__ ex,
    const float* __restrict__ eh, const float* __restrict__ em,
    u16* __restrict__ ws) {
  int i = blockIdx.x * 256 + threadIdx.x;
  if (i < 327680) {                     // Wall^T[k][n], k<640
    int j = i & 7, rest = i >> 3;
    int n = rest & 511, kk = rest >> 9;
    int k = kk * 8 + j;
    float v = (k < 128) ? Wx[n * 128 + k] : Wh[n * 512 + (k - 128)];
    ws[WPACK + i] = f2bf(v);
  } else if (i < 393216) {              // atpack[kk][d][j] = AT[d][kk*8+j]
    int t = i - 327680;
    int j = t & 7, rest = t >> 3;
    int d = rest & 255, kk = rest >> 8;
    ws[ATPACK + t] = f2bf(AT[d * 256 + kk * 8 + j]);
  } else if (i < 393728) {              // wu[n] = dot(Wm[n,:], BT)
    int n = i - 393216;
    float s = 0.f;
    for (int k = 0; k < 256; k += 4) {
      float4 wv = *(const float4*)(Wm + (size_t)n * 256 + k);
      float4 bv = *(const float4*)(BT + k);
      s += wv.x * bv.x + wv.y * bv.y + wv.z * bv.z + wv.w * bv.w;
    }
    ((float*)(ws + WUOFF))[n] = s;
  } else if (i < PACK_ITEMS) {          // epack[kk][col][j]: col0 = e
    int t = i - 393728;
    int j = t & 7, rest = t >> 3;
    int col = rest & 15, kk = rest >> 4;
    int k = kk * 8 + j;
    float v = 0.f;
    if (col == 0)
      v = (k < 128) ? ex[k] : (k < 640) ? eh[k - 128] : em[k - 640];
    ws[EPACK + t] = f2bf(v);
  }
}

// ---------------- prologue 2: Wm2 = Wm @ AT, bf16-packed (validated) -------
__global__ __launch_bounds__(256) void lmu_wm2(
    const float* __restrict__ Wm, const float* __restrict__ AT,
    u16* __restrict__ ws) {
  __shared__ float wmt[16 * 256];
  const int t = threadIdx.x;
  const int nb = blockIdx.x * 16, db = blockIdx.y * 64;
#pragma unroll
  for (int it = 0; it < 4; ++it) {
    int f = it * 256 + t;
    float4 v = *(const float4*)(Wm + (size_t)(nb + (f >> 6)) * 256 + (f & 63) * 4);
    *(float4*)(wmt + (f >> 6) * 256 + (f & 63) * 4) = v;
  }
  __syncthreads();
  const int d = db + (t & 63);
  const int nn = (t >> 6) * 4;
  float acc[4] = {0.f, 0.f, 0.f, 0.f};
  for (int k = 0; k < 256; ++k) {
    float atv = AT[(size_t)k * 256 + d];
#pragma unroll
    for (int i2 = 0; i2 < 4; ++i2) acc[i2] += wmt[(nn + i2) * 256 + k] * atv;
  }
  const int kk = 80 + (d >> 3), j = d & 7;
#pragma unroll
  for (int i2 = 0; i2 < 4; ++i2)
    ws[WPACK + ((size_t)kk * 512 + (nb + nn + i2)) * 8 + j] = f2bf(acc[i2]);
}

// ---------------- main fused GEMM -------------------------------------------
// grid 512 = 128 M-tiles x 4 N-slices (XCD-clustered); 512 thr; LDS 64KB.
// buffer (16384 u16): A [8kb][128r][8] @0, B [8kk][128n][8] @8192.
__global__ __launch_bounds__(512, 4) void lmu_gemm(
    const float* __restrict__ x, const float* __restrict__ h,
    const float* __restrict__ m, const float* __restrict__ BT,
    const u16* __restrict__ ws, float* __restrict__ out) {
  __shared__ __align__(16) u16 smem[2 * 16384];
  const int tid  = threadIdx.x;
  const int lane = tid & 63;
  const int w    = tid >> 6;     // 0..7
  const int wr   = w >> 1;       // 0..3 (32-row slice)
  const int wc   = w & 1;        // 0..1 (64-col slice)
  const int lm   = lane & 15;
  const int kg   = lane >> 4;
  const int bid  = blockIdx.x;
  const int mi   = (bid & 7) | ((bid >> 5) << 3);  // N-slices of same M co-XCD
  const int nsl  = (bid >> 3) & 3;
  const int b0   = mi * 128;
  const int r    = tid & 127;    // staging row
  const int cg   = tid >> 7;     // staging col-group (16 cols)

  const u16* wpk = ws + WPACK;
  const u16* atp = ws + ATPACK;
  const u16* epk = ws + EPACK;

  f32x4 acc[2][4];    // new_h: 2 Mfrag x 4 Nfrag
  f32x4 acc2[2][2];   // new_m: 2 Mfrag x 2 Nfrag
  f32x4 accu[2];      // u (col 0 of epack), wc==0 waves
#pragma unroll
  for (int mt = 0; mt < 2; ++mt) {
#pragma unroll
    for (int ct = 0; ct < 4; ++ct) acc[mt][ct] = (f32x4){0.f, 0.f, 0.f, 0.f};
#pragma unroll
    for (int ct = 0; ct < 2; ++ct) acc2[mt][ct] = (f32x4){0.f, 0.f, 0.f, 0.f};
    accu[mt] = (f32x4){0.f, 0.f, 0.f, 0.f};
  }

  float4 av[4];   // in-flight A slice (row r, cols cg*16..+15 of chunk)

  auto aload = [&](int c) {          // issue early (T14)
    const float* ap;
    if (c < 2)       ap = x + (size_t)(b0 + r) * 128 + c * 64 + cg * 16;
    else if (c < 10) ap = h + (size_t)(b0 + r) * 512 + (c - 2) * 64 + cg * 16;
    else             ap = m + (size_t)(b0 + r) * 256 + (c - 10) * 64 + cg * 16;
#pragma unroll
    for (int i = 0; i < 4; ++i) av[i] = *(const float4*)(ap + i * 4);
  };
  auto bstage = [&](int c) {
    u16* bufB = smem + (c & 1) * 16384 + 8192;
#pragma unroll
    for (int ph = 0; ph < 2; ++ph) {
      int i = ph * 512 + tid;
      gload16(wpk + ((size_t)(c * 8 + (i >> 7)) * 512 + nsl * 128 + (i & 127)) * 8,
              bufB + i * 8);
    }
  };
  auto commit = [&](int c) {         // commit late: cvt + packed ds_write
    u16* bufA = smem + (c & 1) * 16384;
    bf16x8 p0 = {(bf16)av[0].x, (bf16)av[0].y, (bf16)av[0].z, (bf16)av[0].w,
                 (bf16)av[1].x, (bf16)av[1].y, (bf16)av[1].z, (bf16)av[1].w};
    bf16x8 p1 = {(bf16)av[2].x, (bf16)av[2].y, (bf16)av[2].z, (bf16)av[2].w,
                 (bf16)av[3].x, (bf16)av[3].y, (bf16)av[3].z, (bf16)av[3].w};
    *(bf16x8*)(bufA + ((cg * 2 + 0) * 128 + r) * 8) = p0;
    *(bf16x8*)(bufA + ((cg * 2 + 1) * 128 + r) * 8) = p1;
  };
  auto mma = [&](int c) {
    const u16* bufA = smem + (c & 1) * 16384;
    const u16* bufB = bufA + 8192;
#pragma unroll
    for (int ks = 0; ks < 2; ++ks) {
      const int kq = ks * 4 + kg;
      bf16x8 a[2];
#pragma unroll
      for (int mt = 0; mt < 2; ++mt)
        a[mt] = *(const bf16x8*)(bufA + (kq * 128 + wr * 32 + mt * 16 + lm) * 8);
#pragma unroll
      for (int ct = 0; ct < 4; ++ct) {
        bf16x8 b = *(const bf16x8*)(bufB + (kq * 128 + wc * 64 + ct * 16 + lm) * 8);
#pragma unroll
        for (int mt = 0; mt < 2; ++mt)
          acc[mt][ct] = __builtin_amdgcn_mfma_f32_16x16x32_bf16(a[mt], b, acc[mt][ct], 0, 0, 0);
      }
      if (wc == 0) {                 // u-column MFMA (epack, L2-hot 28KB)
        bf16x8 be = *(const bf16x8*)(epk + ((size_t)(c * 8 + kq) * 16 + lm) * 8);
#pragma unroll
        for (int mt = 0; mt < 2; ++mt)
          accu[mt] = __builtin_amdgcn_mfma_f32_16x16x32_bf16(a[mt], be, accu[mt], 0, 0, 0);
      }
      if (c >= 10) {                 // new_m side-GEMM, B direct from L2
#pragma unroll
        for (int ct = 0; ct < 2; ++ct) {
          bf16x8 b = *(const bf16x8*)(atp +
              ((size_t)((c - 10) * 8 + kq) * 256 + nsl * 64 + wc * 32 + ct * 16 + lm) * 8);
#pragma unroll
          for (int mt = 0; mt < 2; ++mt)
            acc2[mt][ct] = __builtin_amdgcn_mfma_f32_16x16x32_bf16(a[mt], b, acc2[mt][ct], 0, 0, 0);
        }
      }
    }
  };

  // ---- pipeline: issue(c+1) -> mma(c) -> commit(c+1) -> barrier ----
  aload(0);
  bstage(0);
  commit(0);
  __syncthreads();
#pragma unroll 2
  for (int c = 0; c < 14; ++c) {
    if (c < 13) { aload(c + 1); bstage(c + 1); }
    mma(c);
    if (c < 13) commit(c + 1);
    __syncthreads();
  }

  // ---- u exchange through dead LDS ----
  float* uL = (float*)smem;
  if (wc == 0 && lm == 0) {
#pragma unroll
    for (int mt = 0; mt < 2; ++mt)
#pragma unroll
      for (int j = 0; j < 4; ++j)
        uL[wr * 32 + mt * 16 + kg * 4 + j] = accu[mt][j];
  }
  __syncthreads();

  // ---- epilogue ----
  const float* wuf = (const float*)(ws + WUOFF);
  float wuv[4], btv[2];
#pragma unroll
  for (int ct = 0; ct < 4; ++ct) wuv[ct] = wuf[nsl * 128 + wc * 64 + ct * 16 + lm];
#pragma unroll
  for (int ct = 0; ct < 2; ++ct) btv[ct] = BT[nsl * 64 + wc * 32 + ct * 16 + lm];
  float* outm = out + (size_t)BATCH * 512;
#pragma unroll
  for (int mt = 0; mt < 2; ++mt)
#pragma unroll
    for (int j = 0; j < 4; ++j) {
      int rl = wr * 32 + mt * 16 + kg * 4 + j;
      size_t row = (size_t)(b0 + rl);
      float uv = uL[rl];
#pragma unroll
      for (int ct = 0; ct < 4; ++ct) {
        float v = acc[mt][ct][j] + uv * wuv[ct];
        out[row * 512 + nsl * 128 + wc * 64 + ct * 16 + lm] = 1.0f / (1.0f + __expf(-v));
      }
#pragma unroll
      for (int ct = 0; ct < 2; ++ct)
        outm[row * 256 + nsl * 64 + wc * 32 + ct * 16 + lm] = acc2[mt][ct][j] + uv * btv[ct];
    }
}

extern "C" void kernel_launch(void* const* d_in, const int* in_sizes, int n_in,
                              void* d_out, int out_size, void* d_ws, size_t ws_size,
                              hipStream_t stream) {
  const float* x  = (const float*)d_in[0];
  const float* h  = (const float*)d_in[1];
  const float* m  = (const float*)d_in[2];
  const float* Wx = (const float*)d_in[3];
  const float* Wh = (const float*)d_in[4];
  const float* Wm = (const float*)d_in[5];
  const float* ex = (const float*)d_in[6];
  const float* eh = (const float*)d_in[7];
  const float* em = (const float*)d_in[8];
  const float* AT = (const float*)d_in[9];
  const float* BT = (const float*)d_in[10];
  float* out = (float*)d_out;
  u16* ws = (u16*)d_ws;   // uses ~1.08 MB

  lmu_pack<<<PACK_ITEMS / 256, 256, 0, stream>>>(Wx, Wh, Wm, AT, BT, ex, eh, em, ws);
  lmu_wm2<<<dim3(32, 4), 256, 0, stream>>>(Wm, AT, ws);
  lmu_gemm<<<512, 512, 0, stream>>>(x, h, m, BT, ws, out);
}

// Round 6
// 61.565 us; speedup vs baseline: 1.2741x; 1.2741x over previous
//
#include <hip/hip_runtime.h>

// ---------------------------------------------------------------------------
// LMU fused cell on MI355X (gfx950).  Round 6: 1 block/CU, counted-vmcnt pipe.
//   new_h = sigmoid([x|h|m] @ [Wx|Wh|Wm@AT]^T + u*(Wm@BT)^T)
//   new_m = m @ AT^T + u*BT^T     u = [x|h|m].e  (via MFMA vs epack col 0)
// lmu_gemm: BM=256, BN=128 (+64 side), BK=64 x 14 chunks, grid 256 = 1/CU.
//   A: f32 global -> regs (coalesced) -> bf16 swizzled LDS (2-buf).
//   B/S: global_load_lds packed (3-buf, issued 2 chunks ahead).
//   Counted s_waitcnt vmcnt(3) + raw s_barrier per chunk (T3/T4).
// ---------------------------------------------------------------------------

typedef __bf16 bf16;
typedef bf16  bf16x4 __attribute__((ext_vector_type(4)));
typedef bf16  bf16x8 __attribute__((ext_vector_type(8)));
typedef float f32x4  __attribute__((ext_vector_type(4)));
typedef unsigned short u16;

#define BATCH 16384
// ws offsets (u16 units) -- layout identical to R5 (validated)
#define WPACK 0          // [896/8][512][8] = 458752  (k>=640 = Wm@AT)
#define ATPACK 458752    // [256/8][256][8] = 65536
#define WUOFF 524288     // 512 f32 (1024 u16)
#define EPACK 525312     // [112][16][8] = 14336 (col0 = e, rest 0)
#define PACK_ITEMS 408064

// LDS (u16 units): A 2 x 16384 (32KB each) | B/S 3 x (8192 B + 4096 S)
#define ABUF(c)  ((c & 1) * 16384)
#define BBUF(c)  (32768 + (c % 3) * 12288)
#define SBUF(c)  (BBUF(c) + 8192)
#define SMEM_U16 69632   // 139,264 bytes

__device__ __forceinline__ u16 f2bf(float f) {
  unsigned u = __builtin_bit_cast(unsigned, f);
  u += 0x7FFFu + ((u >> 16) & 1u);   // RNE
  return (u16)(u >> 16);
}

__device__ __forceinline__ void gload16(const u16* g, u16* l) {
  __builtin_amdgcn_global_load_lds(
      (const __attribute__((address_space(1))) unsigned int*)g,
      (__attribute__((address_space(3))) unsigned int*)l, 16, 0, 0);
}

// ---------------- prologue 1: pack Wx|Wh, AT, wu=Wm@BT, epack (validated) --
__global__ __launch_bounds__(256) void lmu_pack(
    const float* __restrict__ Wx, const float* __restrict__ Wh,
    const float* __restrict__ Wm, const float* __restrict__ AT,
    const float* __restrict__ BT, const float* __restrict__ ex,
    const float* __restrict__ eh, const float* __restrict__ em,
    u16* __restrict__ ws) {
  int i = blockIdx.x * 256 + threadIdx.x;
  if (i < 327680) {                     // Wall^T[k][n], k<640
    int j = i & 7, rest = i >> 3;
    int n = rest & 511, kk = rest >> 9;
    int k = kk * 8 + j;
    float v = (k < 128) ? Wx[n * 128 + k] : Wh[n * 512 + (k - 128)];
    ws[WPACK + i] = f2bf(v);
  } else if (i < 393216) {              // atpack[kk][d][j] = AT[d][kk*8+j]
    int t = i - 327680;
    int j = t & 7, rest = t >> 3;
    int d = rest & 255, kk = rest >> 8;
    ws[ATPACK + t] = f2bf(AT[d * 256 + kk * 8 + j]);
  } else if (i < 393728) {              // wu[n] = dot(Wm[n,:], BT)
    int n = i - 393216;
    float s = 0.f;
    for (int k = 0; k < 256; k += 4) {
      float4 wv = *(const float4*)(Wm + (size_t)n * 256 + k);
      float4 bv = *(const float4*)(BT + k);
      s += wv.x * bv.x + wv.y * bv.y + wv.z * bv.z + wv.w * bv.w;
    }
    ((float*)(ws + WUOFF))[n] = s;
  } else if (i < PACK_ITEMS) {          // epack[kk][col][j]: col0 = e
    int t = i - 393728;
    int j = t & 7, rest = t >> 3;
    int col = rest & 15, kk = rest >> 4;
    int k = kk * 8 + j;
    float v = 0.f;
    if (col == 0)
      v = (k < 128) ? ex[k] : (k < 640) ? eh[k - 128] : em[k - 640];
    ws[EPACK + t] = f2bf(v);
  }
}

// ---------------- prologue 2: Wm2 = Wm @ AT, bf16-packed (validated) -------
__global__ __launch_bounds__(256) void lmu_wm2(
    const float* __restrict__ Wm, const float* __restrict__ AT,
    u16* __restrict__ ws) {
  __shared__ float wmt[16 * 256];
  const int t = threadIdx.x;
  const int nb = blockIdx.x * 16, db = blockIdx.y * 64;
#pragma unroll
  for (int it = 0; it < 4; ++it) {
    int f = it * 256 + t;
    float4 v = *(const float4*)(Wm + (size_t)(nb + (f >> 6)) * 256 + (f & 63) * 4);
    *(float4*)(wmt + (f >> 6) * 256 + (f & 63) * 4) = v;
  }
  __syncthreads();
  const int d = db + (t & 63);
  const int nn = (t >> 6) * 4;
  float acc[4] = {0.f, 0.f, 0.f, 0.f};
  for (int k = 0; k < 256; ++k) {
    float atv = AT[(size_t)k * 256 + d];
#pragma unroll
    for (int i2 = 0; i2 < 4; ++i2) acc[i2] += wmt[(nn + i2) * 256 + k] * atv;
  }
  const int kk = 80 + (d >> 3), j = d & 7;
#pragma unroll
  for (int i2 = 0; i2 < 4; ++i2)
    ws[WPACK + ((size_t)kk * 512 + (nb + nn + i2)) * 8 + j] = f2bf(acc[i2]);
}

// ---------------- main fused GEMM -------------------------------------------
__global__ __launch_bounds__(512, 2) void lmu_gemm(
    const float* __restrict__ x, const float* __restrict__ h,
    const float* __restrict__ m, const float* __restrict__ BT,
    const u16* __restrict__ ws, float* __restrict__ out) {
  __shared__ __align__(16) u16 smem[SMEM_U16];
  const int tid  = threadIdx.x;
  const int lane = tid & 63;
  const int w    = tid >> 6;     // 0..7
  const int wr   = w >> 1;       // 0..3 : 64-row slice
  const int wc   = w & 1;        // 0..1 : 64-col (new_h) / 32-col (new_m)
  const int lm   = lane & 15;
  const int kg   = lane >> 4;
  // XCD-swizzle: 4 N-slices of one M-tile land on the same XCD (bid%8 = XCD)
  const int bid  = blockIdx.x;
  const int xcd  = bid & 7, jj = bid >> 3;
  const int mi   = xcd + 8 * (jj >> 2);   // 0..63
  const int nsl  = jj & 3;                // 0..3
  const int b0   = mi * 256;

  const u16* wpk = ws + WPACK;
  const u16* atp = ws + ATPACK;
  const u16* epk = ws + EPACK;

  f32x4 acc[4][4];    // new_h: 64r x 64c per wave
  f32x4 acc2[4][2];   // new_m: 64r x 32c per wave
  f32x4 accu[4];      // u column (wc==0 waves)
#pragma unroll
  for (int mt = 0; mt < 4; ++mt) {
#pragma unroll
    for (int ct = 0; ct < 4; ++ct) acc[mt][ct] = (f32x4){0.f, 0.f, 0.f, 0.f};
#pragma unroll
    for (int ct = 0; ct < 2; ++ct) acc2[mt][ct] = (f32x4){0.f, 0.f, 0.f, 0.f};
    accu[mt] = (f32x4){0.f, 0.f, 0.f, 0.f};
  }

  float4 av[8];   // in-flight A (256r x 64k f32 / 512 thr = 8 float4 each)

  auto aload = [&](int c) {              // coalesced: flat idx = ph*512+tid
    const float* base;
    int stride, off;
    if (c < 2)       { base = x; stride = 128; off = c * 64; }
    else if (c < 10) { base = h; stride = 512; off = (c - 2) * 64; }
    else             { base = m; stride = 256; off = (c - 10) * 64; }
#pragma unroll
    for (int ph = 0; ph < 8; ++ph) {
      int i = ph * 512 + tid;
      int row = i >> 4, c4 = i & 15;
      av[ph] = *(const float4*)(base + (size_t)(b0 + row) * stride + off + c4 * 4);
    }
  };
  auto commit = [&](int c) {             // cvt + swizzled ds_write (b64)
    u16* bufA = smem + ABUF(c);
#pragma unroll
    for (int ph = 0; ph < 8; ++ph) {
      int i = ph * 512 + tid;
      int row = i >> 4, c4 = i & 15;
      bf16x4 p = {(bf16)av[ph].x, (bf16)av[ph].y, (bf16)av[ph].z, (bf16)av[ph].w};
      *(bf16x4*)(bufA + row * 64 + ((c4 * 4) ^ ((row & 7) << 3))) = p;
    }
  };
  auto bstage = [&](int c) {             // B 16KB + S 8KB via global_load_lds
    u16* bufB = smem + BBUF(c);
    u16* bufS = smem + SBUF(c);
#pragma unroll
    for (int ph = 0; ph < 2; ++ph) {
      int i = ph * 512 + tid;
      gload16(wpk + ((size_t)(c * 8 + (i >> 7)) * 512 + nsl * 128 + (i & 127)) * 8,
              bufB + i * 8);
    }
    int cs = c < 10 ? 0 : c - 10;        // dummy (valid) source for c<10
    gload16(atp + ((size_t)(cs * 8 + (tid >> 6)) * 256 + nsl * 64 + (tid & 63)) * 8,
            bufS + tid * 8);
  };
  auto mma = [&](int c) {
    const u16* bufA = smem + ABUF(c);
    const u16* bufB = smem + BBUF(c);
    const u16* bufS = smem + SBUF(c);
    __builtin_amdgcn_s_setprio(1);
#pragma unroll
    for (int ks = 0; ks < 2; ++ks) {
      const int kq = ks * 4 + kg;
      bf16x8 a[4];
#pragma unroll
      for (int mt = 0; mt < 4; ++mt) {
        int row = wr * 64 + mt * 16 + lm;
        a[mt] = *(const bf16x8*)(bufA + row * 64 + ((kq * 8) ^ ((row & 7) << 3)));
      }
#pragma unroll
      for (int ct = 0; ct < 4; ++ct) {
        bf16x8 b = *(const bf16x8*)(bufB + (kq * 128 + wc * 64 + ct * 16 + lm) * 8);
#pragma unroll
        for (int mt = 0; mt < 4; ++mt)
          acc[mt][ct] = __builtin_amdgcn_mfma_f32_16x16x32_bf16(a[mt], b, acc[mt][ct], 0, 0, 0);
      }
      if (c >= 10) {                     // new_m side-GEMM (B from LDS)
#pragma unroll
        for (int ct = 0; ct < 2; ++ct) {
          bf16x8 b = *(const bf16x8*)(bufS + (kq * 64 + wc * 32 + ct * 16 + lm) * 8);
#pragma unroll
          for (int mt = 0; mt < 4; ++mt)
            acc2[mt][ct] = __builtin_amdgcn_mfma_f32_16x16x32_bf16(a[mt], b, acc2[mt][ct], 0, 0, 0);
        }
      }
      if (wc == 0) {                     // u-column MFMA (epack, L2-hot)
        bf16x8 be = *(const bf16x8*)(epk + ((size_t)(c * 8 + kq) * 16 + lm) * 8);
#pragma unroll
        for (int mt = 0; mt < 4; ++mt)
          accu[mt] = __builtin_amdgcn_mfma_f32_16x16x32_bf16(a[mt], be, accu[mt], 0, 0, 0);
      }
    }
    __builtin_amdgcn_s_setprio(0);
  };

  // ---- prologue: fill pipe (B 2 ahead, A 1 ahead) ----
  aload(0);                 // 8 vmem (oldest)
  bstage(0); bstage(1);     // 6 vmem
  commit(0);                // compiler waits av -> vmcnt(6); leaves bstages
  asm volatile("s_waitcnt vmcnt(3) lgkmcnt(0)" ::: "memory");  // bstage(0) done
  __builtin_amdgcn_s_barrier();

  // ---- main loop: never drain to 0 until the tail ----
#pragma unroll 1
  for (int c = 0; c < 14; ++c) {
    if (c < 13) aload(c + 1);           // 8 vmem, oldest this iter
    if (c < 12) bstage(c + 2);          // 3 vmem, newest
    mma(c);
    if (c < 13) commit(c + 1);          // waits own aloads (vmcnt(3) or (0))
    if (c < 12) {
      asm volatile("s_waitcnt vmcnt(3) lgkmcnt(0)" ::: "memory");
      __builtin_amdgcn_s_barrier();
    } else if (c < 13) {
      asm volatile("s_waitcnt vmcnt(0) lgkmcnt(0)" ::: "memory");
      __builtin_amdgcn_s_barrier();
    }
  }

  // ---- u exchange through dead LDS (bufA0 region, disjoint from bufA1) ----
  float* uL = (float*)smem;
  if (wc == 0 && lm == 0) {
#pragma unroll
    for (int mt = 0; mt < 4; ++mt)
#pragma unroll
      for (int j = 0; j < 4; ++j)
        uL[wr * 64 + mt * 16 + kg * 4 + j] = accu[mt][j];
  }
  __syncthreads();

  // ---- epilogue ----
  const float* wuf = (const float*)(ws + WUOFF);
  float wuv[4], btv[2];
#pragma unroll
  for (int ct = 0; ct < 4; ++ct) wuv[ct] = wuf[nsl * 128 + wc * 64 + ct * 16 + lm];
#pragma unroll
  for (int ct = 0; ct < 2; ++ct) btv[ct] = BT[nsl * 64 + wc * 32 + ct * 16 + lm];
  float* outm = out + (size_t)BATCH * 512;
#pragma unroll
  for (int mt = 0; mt < 4; ++mt)
#pragma unroll
    for (int j = 0; j < 4; ++j) {
      int rl = wr * 64 + mt * 16 + kg * 4 + j;
      size_t row = (size_t)(b0 + rl);
      float uv = uL[rl];
#pragma unroll
      for (int ct = 0; ct < 4; ++ct) {
        float v = acc[mt][ct][j] + uv * wuv[ct];
        out[row * 512 + nsl * 128 + wc * 64 + ct * 16 + lm] = 1.0f / (1.0f + __expf(-v));
      }
#pragma unroll
      for (int ct = 0; ct < 2; ++ct)
        outm[row * 256 + nsl * 64 + wc * 32 + ct * 16 + lm] = acc2[mt][ct][j] + uv * btv[ct];
    }
}

extern "C" void kernel_launch(void* const* d_in, const int* in_sizes, int n_in,
                              void* d_out, int out_size, void* d_ws, size_t ws_size,
                              hipStream_t stream) {
  const float* x  = (const float*)d_in[0];
  const float* h  = (const float*)d_in[1];
  const float* m  = (const float*)d_in[2];
  const float* Wx = (const float*)d_in[3];
  const float* Wh = (const float*)d_in[4];
  const float* Wm = (const float*)d_in[5];
  const float* ex = (const float*)d_in[6];
  const float* eh = (const float*)d_in[7];
  const float* em = (const float*)d_in[8];
  const float* AT = (const float*)d_in[9];
  const float* BT = (const float*)d_in[10];
  float* out = (float*)d_out;
  u16* ws = (u16*)d_ws;   // uses ~1.08 MB

  lmu_pack<<<PACK_ITEMS / 256, 256, 0, stream>>>(Wx, Wh, Wm, AT, BT, ex, eh, em, ws);
  lmu_wm2<<<dim3(32, 4), 256, 0, stream>>>(Wm, AT, ws);
  lmu_gemm<<<256, 512, 0, stream>>>(x, h, m, BT, ws, out);
}